// Round 7
// baseline (533.707 us; speedup 1.0000x reference)
//
#include <hip/hip_runtime.h>
#include <math.h>

// Problem constants
#define T_TOKENS 16384
#define HID      2048
#define NE       64     // experts
#define TOPK     8
// Gap threshold for exact f64 rescue: chunk-promoted f32 logit error is
// ~4e-7 typical / ~3e-6 worst; 1e-4 gives >30x margin (validated round 6).
#define EPS_GAP  1e-4

// ---------------------------------------------------------------------------
// Kernel 1: logits = hidden @ weight^T, no LDS, no barriers.
// Wave tile = 64 tokens (lane = token) x 8 experts (wave-uniform) x full K.
//  - B loads are wave-uniform (pointer derived from readfirstlane'd wave id)
//    -> compiler emits s_load -> SMEM pipe, v_fma_f32 with SGPR operand.
//  - A loads: per-lane float4, 8 per 32-k block; each 128B line is reused
//    8x from L1 (working set 64 lines/wave).
//  - 2048 waves total -> 8 waves/CU (2/SIMD). FMA floor 65.5k cyc/SIMD.
// ---------------------------------------------------------------------------
__global__ __launch_bounds__(256) void logits_kernel(
    const float* __restrict__ hidden,    // [T_TOKENS, HID]
    const float* __restrict__ weight,    // [NE, HID]
    float* __restrict__ out_logits)      // [T_TOKENS, NE]
{
    const int wave = __builtin_amdgcn_readfirstlane((int)(threadIdx.x >> 6));
    const int lane = threadIdx.x & 63;
    const int w    = blockIdx.x * 4 + wave;  // 0..2047
    const int tg   = w >> 3;                 // token group (64 tokens)
    const int es   = w & 7;                  // expert slice (8 experts)
    // tg = w>>3 keeps a token-group's 8 expert-slices in 2 adjacent blocks;
    // A is <= L3 (128 MB), so re-reads are L3 hits regardless.

    const int tok = tg * 64 + lane;
    const float* __restrict__ arow = hidden + (size_t)tok * HID;
    const float* __restrict__ wrow = weight + (size_t)(es * 8) * HID;  // uniform

    float acc[8];
    #pragma unroll
    for (int j = 0; j < 8; ++j) acc[j] = 0.f;

    for (int k0 = 0; k0 < HID; k0 += 32) {
        // A: this lane's 32 k's (8 x b128; divergent addrs but L1-resident)
        float4 a[8];
        #pragma unroll
        for (int q = 0; q < 8; ++q)
            a[q] = *(const float4*)&arow[k0 + 4 * q];

        // fresh f32 partial per 32-k block (chunk-promote: short error chains)
        float ca[8];
        #pragma unroll
        for (int j = 0; j < 8; ++j) ca[j] = 0.f;

        #pragma unroll
        for (int q = 0; q < 8; ++q) {
            #pragma unroll
            for (int j = 0; j < 8; ++j) {
                // wave-uniform address -> s_load_dwordx4 (SMEM pipe)
                const float4 b = *(const float4*)&wrow[(size_t)j * HID + k0 + 4 * q];
                ca[j] = fmaf(a[q].x, b.x, ca[j]);
                ca[j] = fmaf(a[q].y, b.y, ca[j]);
                ca[j] = fmaf(a[q].z, b.z, ca[j]);
                ca[j] = fmaf(a[q].w, b.w, ca[j]);
            }
        }
        #pragma unroll
        for (int j = 0; j < 8; ++j) acc[j] += ca[j];
    }

    // 32 B contiguous per lane (2 x b128 stores)
    float* __restrict__ dst = out_logits + (size_t)tok * NE + es * 8;
    *(float4*)&dst[0] = make_float4(acc[0], acc[1], acc[2], acc[3]);
    *(float4*)&dst[4] = make_float4(acc[4], acc[5], acc[6], acc[7]);
}

// ---------------------------------------------------------------------------
// Kernel 2: per-token top-8 + renormalized softmax (exp cancellation), with
// exact-f64 rescue when adjacent top-9 gaps are below EPS_GAP (validated r6).
// lane = expert; logits row read coalesced (256 B / token).
// ---------------------------------------------------------------------------
__global__ __launch_bounds__(256) void topk_kernel(
    const float* __restrict__ hidden,
    const float* __restrict__ weight,
    const float* __restrict__ logits,    // [T_TOKENS, NE]
    float* __restrict__ out_vals,        // [T_TOKENS, TOPK]
    float* __restrict__ out_idxf)        // [T_TOKENS, TOPK]
{
    const int wave = threadIdx.x >> 6;
    const int lane = threadIdx.x & 63;
    const int tok0 = blockIdx.x * 32 + wave * 8;

    for (int r = 0; r < 8; ++r) {
        const int tok = tok0 + r;
        double cur = (double)logits[(size_t)tok * NE + lane];
        double first = 0.0, s = 0.0, myv = 0.0;
        int myi = 0;
        double prev = 0.0, mingap = 1e30;
        // top-9 scan: gaps guard the 8|9 boundary and the intra-top-8 order
        #pragma unroll
        for (int i = 0; i < TOPK + 1; ++i) {
            double mv = cur;
            int    mi = lane;
            #pragma unroll
            for (int off = 32; off; off >>= 1) {
                const double ov = __shfl_xor(mv, off);
                const int    oi = __shfl_xor(mi, off);
                if (ov > mv || (ov == mv && oi < mi)) { mv = ov; mi = oi; }
            }
            if (i == 0) first = mv;
            else        mingap = fmin(mingap, prev - mv);
            prev = mv;
            if (i < TOPK) {
                const double e = exp(mv - first);
                s += e;
                if (lane == i) { myv = e; myi = mi; }
            }
            if (lane == mi) cur = -INFINITY;
        }

        if (mingap < EPS_GAP) {   // wave-uniform; ~260/16384 tokens expected
            const float* __restrict__ hrow = hidden + (size_t)tok * HID;
            const float* __restrict__ wrow = weight + (size_t)lane * HID;
            double d = 0.0;
            #pragma unroll 4
            for (int k = 0; k < HID; k += 4) {
                const float4 h = *(const float4*)&hrow[k];
                const float4 ww = *(const float4*)&wrow[k];
                d = fma((double)h.x, (double)ww.x, d);
                d = fma((double)h.y, (double)ww.y, d);
                d = fma((double)h.z, (double)ww.z, d);
                d = fma((double)h.w, (double)ww.w, d);
            }
            cur = d; first = 0.0; s = 0.0; myv = 0.0; myi = 0;
            #pragma unroll
            for (int i = 0; i < TOPK; ++i) {
                double mv = cur;
                int    mi = lane;
                #pragma unroll
                for (int off = 32; off; off >>= 1) {
                    const double ov = __shfl_xor(mv, off);
                    const int    oi = __shfl_xor(mi, off);
                    if (ov > mv || (ov == mv && oi < mi)) { mv = ov; mi = oi; }
                }
                if (i == 0) first = mv;
                const double e = exp(mv - first);
                s += e;
                if (lane == i)  { myv = e; myi = mi; }
                if (lane == mi) cur = -INFINITY;
            }
        }

        if (lane < TOPK) {
            out_vals[(size_t)tok * TOPK + lane] = (float)(myv / s);
            out_idxf[(size_t)tok * TOPK + lane] = (float)myi;
        }
    }
}

extern "C" void kernel_launch(void* const* d_in, const int* in_sizes, int n_in,
                              void* d_out, int out_size, void* d_ws, size_t ws_size,
                              hipStream_t stream) {
    const float* hidden = (const float*)d_in[0];   // [16384, 2048] f32
    const float* weight = (const float*)d_in[1];   // [64, 2048] f32

    float* out        = (float*)d_out;
    float* out_logits = out;                                    // 16384*64
    float* out_vals   = out + (size_t)T_TOKENS * NE;            // 16384*8
    float* out_idxf   = out + (size_t)T_TOKENS * NE
                            + (size_t)T_TOKENS * TOPK;          // 16384*8

    // Kernel 1: 2048 waves (64 tok x 8 exp each) = 512 blocks x 4 waves
    hipLaunchKernelGGL(logits_kernel, dim3(512), dim3(256), 0, stream,
                       hidden, weight, out_logits);
    // Kernel 2: 32 tokens/block
    hipLaunchKernelGGL(topk_kernel, dim3(T_TOKENS / 32), dim3(256), 0, stream,
                       hidden, weight, out_logits, out_vals, out_idxf);
}